// Round 1
// 287.949 us; speedup vs baseline: 1.0599x; 1.0599x over previous
//
#include <hip/hip_runtime.h>
#include <math.h>

#define NB 4096     // B
#define LL 200      // L
#define EE 50       // E
#define LP 201      // padded leading dim (odd -> <=2-way LDS bank aliasing)
#define JT 8        // candidates per thread in median counting loop
#define NT 512      // threads per block (8 waves)

// monotonic float -> sortable uint32
__device__ __forceinline__ unsigned f2key(float f) {
    unsigned b = __float_as_uint(f);
    unsigned mask = (b & 0x80000000u) ? 0xFFFFFFFFu : 0x80000000u;
    return b ^ mask;
}
__device__ __forceinline__ float key2f(unsigned kk) {
    unsigned mask = (kk & 0x80000000u) ? 0x80000000u : 0xFFFFFFFFu;
    return __uint_as_float(kk ^ mask);
}

extern "C" __global__ void __launch_bounds__(NT, 4)
rec_fused(const float* __restrict__ emb, const float* __restrict__ ratings,
          const float* __restrict__ W1, const float* __restrict__ b1,
          const float* __restrict__ W2, const float* __restrict__ b2,
          const float* __restrict__ W3, const float* __restrict__ b3,
          const int* __restrict__ uidx, const int* __restrict__ lens,
          const int* __restrict__ midx, float* __restrict__ out)
{
    __shared__ unsigned wK[EE][LP];   // sortable keys, feature-major: 40.2 KB
    __shared__ int      idxL[LL];     // hoisted indices
    __shared__ float    ratL[LL];     // hoisted ratings
    __shared__ unsigned medKey[EE];
    __shared__ float    u[4*EE];      // [min | max | mean | med]
    __shared__ float    x[5*EE];
    __shared__ float    h1[2*EE];
    __shared__ float    h2[EE];
    __shared__ float    wsum[NT/64];

    const int b   = blockIdx.x;
    const int tid = threadIdx.x;
    const int n   = lens[b];
    const int k   = (n - 1) >> 1;     // lower-median index

    if (tid < EE) medKey[tid] = 0xFFFFFFFFu;
    if (tid < n) {                     // stage per-l scalars once (coalesced)
        idxL[tid] = uidx[b*LL + tid];
        ratL[tid] = ratings[b*LL + tid];
    }
    __syncthreads();

    // ---- gather: w[e][l] = emb[idx[l]][e] * rating[l], stored as sortable key
    for (int p = tid; p < n * EE; p += NT) {
        int l = p / EE;
        int e = p - l * EE;
        float wv = emb[(size_t)idxL[l] * EE + e] * ratL[l];
        wK[e][l] = f2key(wv);
    }
    __syncthreads();

    // ---- min / max / mean: serial per feature on wave 0 (bit-exact order);
    // runs concurrently with the median loop executing on waves 1-7.
    if (tid < EE) {
        const int e = tid;
        unsigned kmin = wK[e][0], kmax = kmin;
        float sm = key2f(kmin);
        for (int i = 1; i < n; i++) {
            unsigned kk = wK[e][i];
            kmin = min(kmin, kk);
            kmax = max(kmax, kk);
            sm += key2f(kk);
        }
        u[e]        = key2f(kmin);
        u[EE + e]   = key2f(kmax);
        u[2*EE + e] = sm / (float)n;
    }

    // ---- median: k-th smallest = min{ x : #{xi <= x} >= k+1 }
    const int nc = (n + JT - 1) / JT;
    for (int c = tid; c < nc * EE; c += NT) {
        int jg = c / EE;
        int e  = c - jg * EE;
        int j0 = jg * JT;
        unsigned kj[JT];
        int cnt[JT];
        #pragma unroll
        for (int m2 = 0; m2 < JT; m2++) {
            int j = j0 + m2;
            kj[m2] = (j < n) ? wK[e][j] : 0xFFFFFFFFu;  // sentinel: atomicMin no-op
            cnt[m2] = 0;
        }
        #pragma unroll 2
        for (int i = 0; i < n; i++) {
            unsigned ki = wK[e][i];
            #pragma unroll
            for (int m2 = 0; m2 < JT; m2++) cnt[m2] += (ki <= kj[m2]) ? 1 : 0;
        }
        #pragma unroll
        for (int m2 = 0; m2 < JT; m2++)
            if (cnt[m2] > k) atomicMin(&medKey[e], kj[m2]);
    }
    __syncthreads();

    if (tid < EE) u[3*EE + tid] = key2f(medKey[tid]);
    __syncthreads();

    // ---- L2 norm of u[200]: per-wave shuffle tree + tiny LDS combine
    float v2 = 0.f;
    if (tid < 4*EE) { float t = u[tid]; v2 = t * t; }
    #pragma unroll
    for (int m2 = 1; m2 < 64; m2 <<= 1) v2 += __shfl_xor(v2, m2);
    if ((tid & 63) == 0) wsum[tid >> 6] = v2;
    __syncthreads();
    float tot = 0.f;
    #pragma unroll
    for (int w = 0; w < NT/64; w++) tot += wsum[w];
    const float inv = 1.0f / sqrtf(tot);

    // ---- x = [u/||u||, emb[movie]]
    if (tid < 4*EE)      x[tid] = u[tid] * inv;
    else if (tid < 5*EE) x[tid] = emb[(size_t)midx[b] * EE + (tid - 4*EE)];
    __syncthreads();

    // ---- MLP layer 1: 100 outputs x 4 lanes each (63 MACs + 2 shuffles)
    if (tid < 4 * (2*EE)) {
        const int o = tid >> 2, g = tid & 3;
        float acc = 0.f;
        for (int i = g; i < 5*EE; i += 4) acc += x[i] * W1[i*(2*EE) + o];
        acc += __shfl_xor(acc, 1);
        acc += __shfl_xor(acc, 2);
        if (g == 0) h1[o] = fmaxf(acc + b1[o], 0.f);
    }
    __syncthreads();

    // ---- MLP layer 2: 50 outputs x 8 lanes each
    if (tid < 8 * EE) {
        const int o = tid >> 3, g = tid & 7;
        float acc = 0.f;
        for (int i = g; i < 2*EE; i += 8) acc += h1[i] * W2[i*EE + o];
        acc += __shfl_xor(acc, 1);
        acc += __shfl_xor(acc, 2);
        acc += __shfl_xor(acc, 4);
        if (g == 0) h2[o] = fmaxf(acc + b2[o], 0.f);
    }
    __syncthreads();

    // ---- output: full-wave shuffle dot + sigmoid
    if (tid < 64) {
        float v = (tid < EE) ? h2[tid] * W3[tid] : 0.f;
        #pragma unroll
        for (int m2 = 1; m2 < 64; m2 <<= 1) v += __shfl_xor(v, m2);
        if (tid == 0) out[b] = 1.0f / (1.0f + expf(-(v + b3[0])));
    }
}

extern "C" void kernel_launch(void* const* d_in, const int* in_sizes, int n_in,
                              void* d_out, int out_size, void* d_ws, size_t ws_size,
                              hipStream_t stream) {
    const float* emb     = (const float*)d_in[0];
    const float* ratings = (const float*)d_in[1];
    const float* W1      = (const float*)d_in[2];
    const float* b1      = (const float*)d_in[3];
    const float* W2      = (const float*)d_in[4];
    const float* b2      = (const float*)d_in[5];
    const float* W3      = (const float*)d_in[6];
    const float* b3      = (const float*)d_in[7];
    const int*   uidx    = (const int*)d_in[8];
    const int*   lens    = (const int*)d_in[9];
    const int*   midx    = (const int*)d_in[10];
    float* out = (float*)d_out;

    hipLaunchKernelGGL(rec_fused, dim3(NB), dim3(NT), 0, stream,
                       emb, ratings, W1, b1, W2, b2, W3, b3, uidx, lens, midx, out);
}

// Round 2
// 162.798 us; speedup vs baseline: 1.8747x; 1.7687x over previous
//
#include <hip/hip_runtime.h>
#include <math.h>

#define NB 4096     // B
#define LL 200      // L
#define EE 50       // E
#define NT 512      // threads per block (8 waves)
#define GG 8        // lanes per feature group
#define IT 25       // ceil(LL/GG) items held in registers per lane

// monotonic float -> sortable uint32 (order-preserving bijection)
__device__ __forceinline__ unsigned f2key(float f) {
    unsigned b = __float_as_uint(f);
    unsigned mask = (b & 0x80000000u) ? 0xFFFFFFFFu : 0x80000000u;
    return b ^ mask;
}
__device__ __forceinline__ float key2f(unsigned kk) {
    unsigned mask = (kk & 0x80000000u) ? 0x80000000u : 0xFFFFFFFFu;
    return __uint_as_float(kk ^ mask);
}

extern "C" __global__ void __launch_bounds__(NT, 6)
rec_fused(const float* __restrict__ emb, const float* __restrict__ ratings,
          const float* __restrict__ W1, const float* __restrict__ b1,
          const float* __restrict__ W2, const float* __restrict__ b2,
          const float* __restrict__ W3, const float* __restrict__ b3,
          const int* __restrict__ uidx, const int* __restrict__ lens,
          const int* __restrict__ midx, float* __restrict__ out)
{
    __shared__ int   idxL[LL];
    __shared__ float ratL[LL];
    __shared__ float u[4*EE];      // [min | max | mean | med]
    __shared__ float x[5*EE];
    __shared__ float h1[2*EE];
    __shared__ float h2[EE];
    __shared__ float wsum[NT/64];

    const int b   = blockIdx.x;
    const int tid = threadIdx.x;
    const int n   = lens[b];
    const int k   = (n - 1) >> 1;     // 0-based lower-median rank

    // stage per-l scalars once (coalesced)
    if (tid < n) {
        idxL[tid] = uidx[b*LL + tid];
        ratL[tid] = ratings[b*LL + tid];
    }
    __syncthreads();

    const int f = tid >> 3;   // feature id (0..63; active if < 50)
    const int g = tid & 7;    // lane within 8-lane group

    if (f < EE) {
        // ---- gather this feature's items into registers: l = g, g+8, ...
        unsigned it[IT];
        #pragma unroll
        for (int t = 0; t < IT; t++) {
            const int l = g + (t << 3);
            unsigned kk = 0xFFFFFFFFu;               // sentinel (> any real key)
            if (l < n)
                kk = f2key(emb[(size_t)idxL[l] * EE + f] * ratL[l]);
            it[t] = kk;
        }

        // ---- min / max / sum over the group (guarded; sentinel-safe)
        unsigned kmin = 0xFFFFFFFFu, kmax = 0u;
        float sm = 0.f;
        #pragma unroll
        for (int t = 0; t < IT; t++) {
            const int l = g + (t << 3);
            if (l < n) {
                const unsigned kk = it[t];
                kmin = min(kmin, kk);
                kmax = max(kmax, kk);
                sm  += key2f(kk);
            }
        }
        #pragma unroll
        for (int m2 = 1; m2 < GG; m2 <<= 1) {
            kmin = min(kmin, (unsigned)__shfl_xor((int)kmin, m2));
            kmax = max(kmax, (unsigned)__shfl_xor((int)kmax, m2));
            sm  += __shfl_xor(sm, m2);
        }

        // ---- median: radix bit-select on sortable keys, early-exit on
        //      unique bracket. Invariants at bit bpos:
        //      window = [prefix, prefix + 2^(bpos+1)), w = #items in window,
        //      cLow = #{x < prefix}. k-th smallest always inside window.
        unsigned prefix = 0u, med = 0u;
        int cLow = 0, w = n;
        int shift = 33;                     // 33 = not found; 32 = full-range scan
        if (w == 1) shift = 32;
        for (int bpos = 31; bpos >= 0 && shift > 32; --bpos) {
            const unsigned tryk = prefix | (1u << bpos);
            int c = 0;                      // #{x < tryk}; sentinels never count
            #pragma unroll
            for (int t = 0; t < IT; t++) c += (it[t] < tryk) ? 1 : 0;
            c += __shfl_xor(c, 1);
            c += __shfl_xor(c, 2);
            c += __shfl_xor(c, 4);
            const int lower = c - cLow;     // #items in [prefix, tryk)
            if (c > k) {                    // k-th is in lower half
                w = lower;
            } else {                        // k-th is in upper half
                prefix = tryk;
                cLow = c;
                w -= lower;
            }
            if (w == 1) shift = bpos;       // unique item in [prefix, prefix+2^bpos)
        }
        if (shift <= 32) {
            // scan for the unique member of the window, group-min reduce
            unsigned mv = 0xFFFFFFFFu;
            if (shift >= 32) {
                #pragma unroll
                for (int t = 0; t < IT; t++) mv = min(mv, it[t]);
            } else {
                const unsigned pp = prefix >> shift;
                #pragma unroll
                for (int t = 0; t < IT; t++) {
                    const unsigned xk = it[t];
                    if ((xk >> shift) == pp) mv = min(mv, xk);
                }
            }
            #pragma unroll
            for (int m2 = 1; m2 < GG; m2 <<= 1)
                mv = min(mv, (unsigned)__shfl_xor((int)mv, m2));
            med = mv;
        } else {
            med = prefix;                   // all bits resolved (duplicates case)
        }

        if (g == 0) {
            u[f]        = key2f(kmin);
            u[EE + f]   = key2f(kmax);
            u[2*EE + f] = sm / (float)n;
            u[3*EE + f] = key2f(med);
        }
    }
    __syncthreads();

    // ---- L2 norm of u[200]: per-wave shuffle tree + tiny LDS combine
    float v2 = 0.f;
    if (tid < 4*EE) { const float t = u[tid]; v2 = t * t; }
    #pragma unroll
    for (int m2 = 1; m2 < 64; m2 <<= 1) v2 += __shfl_xor(v2, m2);
    if ((tid & 63) == 0) wsum[tid >> 6] = v2;
    __syncthreads();
    float tot = 0.f;
    #pragma unroll
    for (int wv = 0; wv < NT/64; wv++) tot += wsum[wv];
    const float inv = 1.0f / sqrtf(tot);

    // ---- x = [u/||u||, emb[movie]]
    if (tid < 4*EE)      x[tid] = u[tid] * inv;
    else if (tid < 5*EE) x[tid] = emb[(size_t)midx[b] * EE + (tid - 4*EE)];
    __syncthreads();

    // ---- MLP layer 1: 100 outputs x 4 lanes each
    if (tid < 4 * (2*EE)) {
        const int o = tid >> 2, gg = tid & 3;
        float acc = 0.f;
        for (int i = gg; i < 5*EE; i += 4) acc += x[i] * W1[i*(2*EE) + o];
        acc += __shfl_xor(acc, 1);
        acc += __shfl_xor(acc, 2);
        if (gg == 0) h1[o] = fmaxf(acc + b1[o], 0.f);
    }
    __syncthreads();

    // ---- MLP layer 2: 50 outputs x 8 lanes each
    if (tid < 8 * EE) {
        const int o = tid >> 3, gg = tid & 7;
        float acc = 0.f;
        for (int i = gg; i < 2*EE; i += 8) acc += h1[i] * W2[i*EE + o];
        acc += __shfl_xor(acc, 1);
        acc += __shfl_xor(acc, 2);
        acc += __shfl_xor(acc, 4);
        if (gg == 0) h2[o] = fmaxf(acc + b2[o], 0.f);
    }
    __syncthreads();

    // ---- output: full-wave shuffle dot + sigmoid
    if (tid < 64) {
        float v = (tid < EE) ? h2[tid] * W3[tid] : 0.f;
        #pragma unroll
        for (int m2 = 1; m2 < 64; m2 <<= 1) v += __shfl_xor(v, m2);
        if (tid == 0) out[b] = 1.0f / (1.0f + expf(-(v + b3[0])));
    }
}

extern "C" void kernel_launch(void* const* d_in, const int* in_sizes, int n_in,
                              void* d_out, int out_size, void* d_ws, size_t ws_size,
                              hipStream_t stream) {
    const float* emb     = (const float*)d_in[0];
    const float* ratings = (const float*)d_in[1];
    const float* W1      = (const float*)d_in[2];
    const float* b1      = (const float*)d_in[3];
    const float* W2      = (const float*)d_in[4];
    const float* b2      = (const float*)d_in[5];
    const float* W3      = (const float*)d_in[6];
    const float* b3      = (const float*)d_in[7];
    const int*   uidx    = (const int*)d_in[8];
    const int*   lens    = (const int*)d_in[9];
    const int*   midx    = (const int*)d_in[10];
    float* out = (float*)d_out;

    hipLaunchKernelGGL(rec_fused, dim3(NB), dim3(NT), 0, stream,
                       emb, ratings, W1, b1, W2, b2, W3, b3, uidx, lens, midx, out);
}

// Round 3
// 162.229 us; speedup vs baseline: 1.8812x; 1.0035x over previous
//
#include <hip/hip_runtime.h>
#include <math.h>

#define NB 4096     // B
#define LL 200      // L
#define EE 50       // E
#define NT 448      // threads per block (7 waves; groups 0..55, 50 active)
#define GG 8        // lanes per feature group
#define IT 25       // ceil(LL/GG) items held in registers per lane
#define SW 8        // small-set threshold (survivor buffer width)

// monotonic float -> sortable uint32 (order-preserving bijection)
__device__ __forceinline__ unsigned f2key(float f) {
    unsigned b = __float_as_uint(f);
    unsigned mask = (b & 0x80000000u) ? 0xFFFFFFFFu : 0x80000000u;
    return b ^ mask;
}
__device__ __forceinline__ float key2f(unsigned kk) {
    unsigned mask = (kk & 0x80000000u) ? 0x80000000u : 0xFFFFFFFFu;
    return __uint_as_float(kk ^ mask);
}

extern "C" __global__ void __launch_bounds__(NT, 4)
rec_fused(const float* __restrict__ emb, const float* __restrict__ ratings,
          const float* __restrict__ W1, const float* __restrict__ b1,
          const float* __restrict__ W2, const float* __restrict__ b2,
          const float* __restrict__ W3, const float* __restrict__ b3,
          const int* __restrict__ uidx, const int* __restrict__ lens,
          const int* __restrict__ midx, float* __restrict__ out)
{
    __shared__ int      idxL[LL];
    __shared__ float    ratL[LL];
    __shared__ unsigned sbuf[NT/GG][SW];   // per-group median survivors
    __shared__ int      scnt[NT/GG];
    __shared__ float    u[4*EE];           // [min | max | mean | med]
    __shared__ float    x[5*EE];
    __shared__ float    h1[2*EE];
    __shared__ float    h2[EE];
    __shared__ float    wsum[NT/64];

    const int b   = blockIdx.x;
    const int tid = threadIdx.x;
    const int n   = lens[b];
    const int k   = (n - 1) >> 1;     // 0-based lower-median rank

    if (tid < NT/GG) scnt[tid] = 0;
    if (tid < n) {                     // stage per-l scalars once (coalesced)
        idxL[tid] = uidx[b*LL + tid];
        ratL[tid] = ratings[b*LL + tid];
    }
    __syncthreads();

    const int f = tid >> 3;   // feature id (0..55; active if < 50)
    const int g = tid & 7;    // lane within 8-lane group

    if (f < EE) {
        // ---- gather this feature's items into registers: l = g, g+8, ...
        unsigned it[IT];
        #pragma unroll
        for (int t = 0; t < IT; t++) {
            const int l = g + (t << 3);
            unsigned kk = 0xFFFFFFFFu;               // sentinel (> any real key)
            if (l < n)
                kk = f2key(emb[(size_t)idxL[l] * EE + f] * ratL[l]);
            it[t] = kk;
        }

        // ---- min / max / sum over the group (guarded; bit-exact vs ref)
        unsigned kmin = 0xFFFFFFFFu, kmax = 0u;
        float sm = 0.f;
        #pragma unroll
        for (int t = 0; t < IT; t++) {
            const int l = g + (t << 3);
            if (l < n) {
                const unsigned kk = it[t];
                kmin = min(kmin, kk);
                kmax = max(kmax, kk);
                sm  += key2f(kk);
            }
        }
        #pragma unroll
        for (int m2 = 1; m2 < GG; m2 <<= 1) {
            kmin = min(kmin, (unsigned)__shfl_xor((int)kmin, m2));
            kmax = max(kmax, (unsigned)__shfl_xor((int)kmax, m2));
            sm  += __shfl_xor(sm, m2);
        }

        // ---- median: exact interpolation-select on sortable keys.
        // Invariant: cLO = #{x < LO} <= k < cHI = #{x < HI}; median key in [LO,HI).
        // Pivot by float-space interpolation (expected ~3-5 passes); key-space
        // bisection after 8 passes guarantees termination; small-set finish
        // (<= SW survivors) resolves the rank directly.
        unsigned LO = kmin, HI = kmax + 1u;   // finite keys <= 0xFF7FFFFF: no wrap
        int cLO = 0, cHI = n;
        unsigned med = 0u;
        bool small = false;
        int pass = 0;
        for (;;) {
            if (HI - LO == 1u) { med = LO; break; }   // all window items equal
            const int w = cHI - cLO;
            if (w <= SW) { small = true; break; }
            unsigned P;
            if (pass < 8) {        // LO/HI decode to finite floats here
                const float vlo  = key2f(LO);
                const float vhi  = key2f(HI - 1u);
                const float frac = (float)(k - cLO + 1) / (float)(w + 1);
                P = f2key(vlo + (vhi - vlo) * frac);
            } else {               // guaranteed-progress bisection
                P = LO + ((HI - LO) >> 1);
            }
            if (P <= LO) P = LO + 1u;      // strict interior: interval shrinks
            if (P >= HI) P = HI - 1u;
            int c = 0;                      // #{x < P}; sentinels never count
            #pragma unroll
            for (int t = 0; t < IT; t++) c += (it[t] < P) ? 1 : 0;
            c += __shfl_xor(c, 1);
            c += __shfl_xor(c, 2);
            c += __shfl_xor(c, 4);
            if (c > k) { HI = P; cHI = c; }
            else       { LO = P; cLO = c; }
            pass++;
        }
        if (small) {
            const int grp = tid >> 3;       // block-wide group id (wave-local)
            const int w   = cHI - cLO;      // #survivors, <= SW
            const int r   = k - cLO;        // target rank among survivors
            #pragma unroll
            for (int t = 0; t < IT; t++) {
                const unsigned kk = it[t];
                if (kk >= LO && kk < HI) {
                    const int pos = atomicAdd(&scnt[grp], 1);
                    if (pos < SW) sbuf[grp][pos] = kk;
                }
            }
            // same-wave LDS ordering: compiler inserts lgkmcnt waits on the
            // aliasing reads below; groups never span waves.
            const unsigned sv = (g < w) ? sbuf[grp][g] : 0xFFFFFFFFu;
            int cLess = 0, cLeq = 0;
            for (int j = 0; j < w; j++) {
                const unsigned o = sbuf[grp][j];
                cLess += (o <  sv) ? 1 : 0;
                cLeq  += (o <= sv) ? 1 : 0;
            }
            unsigned cand = (g < w && cLess <= r && r < cLeq) ? sv : 0xFFFFFFFFu;
            #pragma unroll
            for (int m2 = 1; m2 < GG; m2 <<= 1)
                cand = min(cand, (unsigned)__shfl_xor((int)cand, m2));
            med = cand;
        }

        if (g == 0) {
            u[f]        = key2f(kmin);
            u[EE + f]   = key2f(kmax);
            u[2*EE + f] = sm / (float)n;
            u[3*EE + f] = key2f(med);
        }
    }
    __syncthreads();

    // ---- L2 norm of u[200]: per-wave shuffle tree + tiny LDS combine
    float v2 = 0.f;
    if (tid < 4*EE) { const float t = u[tid]; v2 = t * t; }
    #pragma unroll
    for (int m2 = 1; m2 < 64; m2 <<= 1) v2 += __shfl_xor(v2, m2);
    if ((tid & 63) == 0) wsum[tid >> 6] = v2;
    __syncthreads();
    float tot = 0.f;
    #pragma unroll
    for (int wv = 0; wv < NT/64; wv++) tot += wsum[wv];
    const float inv = 1.0f / sqrtf(tot);

    // ---- x = [u/||u||, emb[movie]]
    if (tid < 4*EE)      x[tid] = u[tid] * inv;
    else if (tid < 5*EE) x[tid] = emb[(size_t)midx[b] * EE + (tid - 4*EE)];
    __syncthreads();

    // ---- MLP layer 1: 100 outputs x 4 lanes each
    if (tid < 4 * (2*EE)) {
        const int o = tid >> 2, gg = tid & 3;
        float acc = 0.f;
        for (int i = gg; i < 5*EE; i += 4) acc += x[i] * W1[i*(2*EE) + o];
        acc += __shfl_xor(acc, 1);
        acc += __shfl_xor(acc, 2);
        if (gg == 0) h1[o] = fmaxf(acc + b1[o], 0.f);
    }
    __syncthreads();

    // ---- MLP layer 2: 50 outputs x 8 lanes each
    if (tid < 8 * EE) {
        const int o = tid >> 3, gg = tid & 7;
        float acc = 0.f;
        for (int i = gg; i < 2*EE; i += 8) acc += h1[i] * W2[i*EE + o];
        acc += __shfl_xor(acc, 1);
        acc += __shfl_xor(acc, 2);
        acc += __shfl_xor(acc, 4);
        if (gg == 0) h2[o] = fmaxf(acc + b2[o], 0.f);
    }
    __syncthreads();

    // ---- output: full-wave shuffle dot + sigmoid
    if (tid < 64) {
        float v = (tid < EE) ? h2[tid] * W3[tid] : 0.f;
        #pragma unroll
        for (int m2 = 1; m2 < 64; m2 <<= 1) v += __shfl_xor(v, m2);
        if (tid == 0) out[b] = 1.0f / (1.0f + expf(-(v + b3[0])));
    }
}

extern "C" void kernel_launch(void* const* d_in, const int* in_sizes, int n_in,
                              void* d_out, int out_size, void* d_ws, size_t ws_size,
                              hipStream_t stream) {
    const float* emb     = (const float*)d_in[0];
    const float* ratings = (const float*)d_in[1];
    const float* W1      = (const float*)d_in[2];
    const float* b1      = (const float*)d_in[3];
    const float* W2      = (const float*)d_in[4];
    const float* b2      = (const float*)d_in[5];
    const float* W3      = (const float*)d_in[6];
    const float* b3      = (const float*)d_in[7];
    const int*   uidx    = (const int*)d_in[8];
    const int*   lens    = (const int*)d_in[9];
    const int*   midx    = (const int*)d_in[10];
    float* out = (float*)d_out;

    hipLaunchKernelGGL(rec_fused, dim3(NB), dim3(NT), 0, stream,
                       emb, ratings, W1, b1, W2, b2, W3, b3, uidx, lens, midx, out);
}

// Round 4
// 140.166 us; speedup vs baseline: 2.1774x; 1.1574x over previous
//
#include <hip/hip_runtime.h>
#include <math.h>

#define NB 4096     // B
#define LL 200      // L
#define EE 50       // E
#define LP 201      // padded words per feature row (odd stride mod 32 -> cheap)
#define NT 512      // threads per block (8 waves)
#define GG 8        // lanes per feature group
#define IT 25       // ceil(LL/GG) items held in registers per lane
#define SW 8        // small-set threshold (survivor buffer width)

// monotonic float -> sortable uint32 (order-preserving bijection)
__device__ __forceinline__ unsigned f2key(float f) {
    unsigned b = __float_as_uint(f);
    unsigned mask = (b & 0x80000000u) ? 0xFFFFFFFFu : 0x80000000u;
    return b ^ mask;
}
__device__ __forceinline__ float key2f(unsigned kk) {
    unsigned mask = (kk & 0x80000000u) ? 0x80000000u : 0xFFFFFFFFu;
    return __uint_as_float(kk ^ mask);
}

extern "C" __global__ void __launch_bounds__(NT, 6)
rec_fused(const float* __restrict__ emb, const float* __restrict__ ratings,
          const float* __restrict__ W1, const float* __restrict__ b1,
          const float* __restrict__ W2, const float* __restrict__ b2,
          const float* __restrict__ W3, const float* __restrict__ b3,
          const int* __restrict__ uidx, const int* __restrict__ lens,
          const int* __restrict__ midx, float* __restrict__ out)
{
    __shared__ unsigned wK[EE][LP];        // 40.2 KB transposed key tile
    __shared__ int      idxL[LL];
    __shared__ float    ratL[LL];
    __shared__ unsigned sbuf[NT/GG][SW];   // per-group median survivors
    __shared__ int      scnt[NT/GG];
    __shared__ float    u[4*EE];           // [min | max | mean | med]
    __shared__ float    x[5*EE];
    __shared__ float    h1[2*EE];
    __shared__ float    h2[EE];
    __shared__ float    wsum[NT/64];

    const int b   = blockIdx.x;
    const int tid = threadIdx.x;
    const int n   = lens[b];
    const int k   = (n - 1) >> 1;     // 0-based lower-median rank

    if (tid < NT/GG) scnt[tid] = 0;
    if (tid < n) {                     // stage per-l scalars once (coalesced)
        idxL[tid] = uidx[b*LL + tid];
        ratL[tid] = ratings[b*LL + tid];
    }
    __syncthreads();

    // ---- gather: coalesced float2 row reads, transpose into LDS key tile.
    // Work scales with n (avg ~5 iters) and uses all 512 lanes.
    const int np2 = n * (EE/2);
    for (int p = tid; p < np2; p += NT) {
        const int l  = p / (EE/2);
        const int e2 = p - l * (EE/2);
        const float2 ev = ((const float2*)emb)[(size_t)idxL[l] * (EE/2) + e2];
        const float  r  = ratL[l];
        wK[2*e2    ][l] = f2key(ev.x * r);
        wK[2*e2 + 1][l] = f2key(ev.y * r);
    }
    __syncthreads();

    const int f = tid >> 3;   // feature id (0..63; active if < 50)
    const int g = tid & 7;    // lane within 8-lane group

    if (f < EE) {
        // ---- distribute this feature's items LDS -> registers; fused
        // min/max/sum (same per-lane t-order as before => bit-exact mean)
        unsigned it[IT];
        unsigned kmin = 0xFFFFFFFFu, kmax = 0u;
        float sm = 0.f;
        #pragma unroll
        for (int t = 0; t < IT; t++) {
            const int l = g + (t << 3);
            unsigned kk = 0xFFFFFFFFu;               // sentinel (> any real key)
            if (l < n) {
                kk = wK[f][l];
                kmin = min(kmin, kk);
                kmax = max(kmax, kk);
                sm  += key2f(kk);
            }
            it[t] = kk;
        }
        #pragma unroll
        for (int m2 = 1; m2 < GG; m2 <<= 1) {
            kmin = min(kmin, (unsigned)__shfl_xor((int)kmin, m2));
            kmax = max(kmax, (unsigned)__shfl_xor((int)kmax, m2));
            sm  += __shfl_xor(sm, m2);
        }

        // ---- median: exact interpolation-select on sortable keys.
        // Invariant: cLO = #{x < LO} <= k < cHI = #{x < HI}; median in [LO,HI).
        unsigned LO = kmin, HI = kmax + 1u;   // finite keys: no wrap
        int cLO = 0, cHI = n;
        unsigned med = 0u;
        bool small = false;
        int pass = 0;
        for (;;) {
            if (HI - LO == 1u) { med = LO; break; }   // window collapsed
            const int w = cHI - cLO;
            if (w <= SW) { small = true; break; }
            unsigned P;
            if (pass < 8) {        // float-space interpolation pivot
                const float vlo  = key2f(LO);
                const float vhi  = key2f(HI - 1u);
                const float frac = (float)(k - cLO + 1) / (float)(w + 1);
                P = f2key(vlo + (vhi - vlo) * frac);
            } else {               // guaranteed-progress key-space bisection
                P = LO + ((HI - LO) >> 1);
            }
            if (P <= LO) P = LO + 1u;      // strict interior: interval shrinks
            if (P >= HI) P = HI - 1u;
            int c = 0;                      // #{x < P}; sentinels never count
            #pragma unroll
            for (int t = 0; t < IT; t++) c += (it[t] < P) ? 1 : 0;
            c += __shfl_xor(c, 1);
            c += __shfl_xor(c, 2);
            c += __shfl_xor(c, 4);
            if (c > k) { HI = P; cHI = c; }
            else       { LO = P; cLO = c; }
            pass++;
        }
        if (small) {
            const int grp = tid >> 3;       // block-wide group id (wave-local)
            const int w   = cHI - cLO;      // #survivors, <= SW
            const int r   = k - cLO;        // target rank among survivors
            #pragma unroll
            for (int t = 0; t < IT; t++) {
                const unsigned kk = it[t];
                if (kk >= LO && kk < HI) {
                    const int pos = atomicAdd(&scnt[grp], 1);
                    if (pos < SW) sbuf[grp][pos] = kk;
                }
            }
            // same-wave LDS ordering: lgkmcnt waits cover the aliasing reads
            const unsigned sv = (g < w) ? sbuf[grp][g] : 0xFFFFFFFFu;
            int cLess = 0, cLeq = 0;
            for (int j = 0; j < w; j++) {
                const unsigned o = sbuf[grp][j];
                cLess += (o <  sv) ? 1 : 0;
                cLeq  += (o <= sv) ? 1 : 0;
            }
            unsigned cand = (g < w && cLess <= r && r < cLeq) ? sv : 0xFFFFFFFFu;
            #pragma unroll
            for (int m2 = 1; m2 < GG; m2 <<= 1)
                cand = min(cand, (unsigned)__shfl_xor((int)cand, m2));
            med = cand;
        }

        if (g == 0) {
            u[f]        = key2f(kmin);
            u[EE + f]   = key2f(kmax);
            u[2*EE + f] = sm / (float)n;
            u[3*EE + f] = key2f(med);
        }
    }
    __syncthreads();

    // ---- L2 norm of u[200]: per-wave shuffle tree + tiny LDS combine
    float v2 = 0.f;
    if (tid < 4*EE) { const float t = u[tid]; v2 = t * t; }
    #pragma unroll
    for (int m2 = 1; m2 < 64; m2 <<= 1) v2 += __shfl_xor(v2, m2);
    if ((tid & 63) == 0) wsum[tid >> 6] = v2;
    __syncthreads();
    float tot = 0.f;
    #pragma unroll
    for (int wv = 0; wv < NT/64; wv++) tot += wsum[wv];
    const float inv = 1.0f / sqrtf(tot);

    // ---- x = [u/||u||, emb[movie]]
    if (tid < 4*EE)      x[tid] = u[tid] * inv;
    else if (tid < 5*EE) x[tid] = emb[(size_t)midx[b] * EE + (tid - 4*EE)];
    __syncthreads();

    // ---- MLP layer 1: 100 outputs x 4 lanes each
    if (tid < 4 * (2*EE)) {
        const int o = tid >> 2, gg = tid & 3;
        float acc = 0.f;
        for (int i = gg; i < 5*EE; i += 4) acc += x[i] * W1[i*(2*EE) + o];
        acc += __shfl_xor(acc, 1);
        acc += __shfl_xor(acc, 2);
        if (gg == 0) h1[o] = fmaxf(acc + b1[o], 0.f);
    }
    __syncthreads();

    // ---- MLP layer 2: 50 outputs x 8 lanes each
    if (tid < 8 * EE) {
        const int o = tid >> 3, gg = tid & 7;
        float acc = 0.f;
        for (int i = gg; i < 2*EE; i += 8) acc += h1[i] * W2[i*EE + o];
        acc += __shfl_xor(acc, 1);
        acc += __shfl_xor(acc, 2);
        acc += __shfl_xor(acc, 4);
        if (gg == 0) h2[o] = fmaxf(acc + b2[o], 0.f);
    }
    __syncthreads();

    // ---- output: full-wave shuffle dot + sigmoid
    if (tid < 64) {
        float v = (tid < EE) ? h2[tid] * W3[tid] : 0.f;
        #pragma unroll
        for (int m2 = 1; m2 < 64; m2 <<= 1) v += __shfl_xor(v, m2);
        if (tid == 0) out[b] = 1.0f / (1.0f + expf(-(v + b3[0])));
    }
}

extern "C" void kernel_launch(void* const* d_in, const int* in_sizes, int n_in,
                              void* d_out, int out_size, void* d_ws, size_t ws_size,
                              hipStream_t stream) {
    const float* emb     = (const float*)d_in[0];
    const float* ratings = (const float*)d_in[1];
    const float* W1      = (const float*)d_in[2];
    const float* b1      = (const float*)d_in[3];
    const float* W2      = (const float*)d_in[4];
    const float* b2      = (const float*)d_in[5];
    const float* W3      = (const float*)d_in[6];
    const float* b3      = (const float*)d_in[7];
    const int*   uidx    = (const int*)d_in[8];
    const int*   lens    = (const int*)d_in[9];
    const int*   midx    = (const int*)d_in[10];
    float* out = (float*)d_out;

    hipLaunchKernelGGL(rec_fused, dim3(NB), dim3(NT), 0, stream,
                       emb, ratings, W1, b1, W2, b2, W3, b3, uidx, lens, midx, out);
}